// Round 3
// baseline (1015.132 us; speedup 1.0000x reference)
//
#include <hip/hip_runtime.h>
#include <hip/hip_bf16.h>

#define EPS 1e-5f
#define CAP 128           // slots per dst bucket (deg ~ Poisson(32); P(>=128) ~ 1e-40)
#define CSTRIDE 32        // cursor padding: 32 ints = 128 B, one cacheline per dst

__device__ __forceinline__ unsigned short f2bf(float f) {
  __hip_bfloat16 h = __float2bfloat16(f);   // RNE
  return *(unsigned short*)&h;
}
__device__ __forceinline__ float bf2f(unsigned short u) {
  union { unsigned int i; float f; } v; v.i = ((unsigned int)u) << 16; return v.f;
}

// ---------- prep: fold BN0 into W1 (W1p = diag(s0)W1, c1 = t0@W1), BN1 affine (s1,u1) ----------
__global__ void k_prep(const float* __restrict__ W1, const float* __restrict__ b1,
                       const float* __restrict__ g0, const float* __restrict__ be0,
                       const float* __restrict__ m0, const float* __restrict__ v0,
                       const float* __restrict__ g1, const float* __restrict__ be1,
                       const float* __restrict__ m1, const float* __restrict__ v1,
                       float* __restrict__ W1p, float* __restrict__ c1,
                       float* __restrict__ s1, float* __restrict__ u1) {
  int j = threadIdx.x;  // 128 threads, one per output column
  float acc = 0.f;
  for (int k = 0; k < 128; ++k) {
    float s0 = g0[k] * rsqrtf(v0[k] + EPS);
    float t0 = be0[k] - m0[k] * s0;
    float w = W1[k * 128 + j];
    W1p[k * 128 + j] = s0 * w;
    acc = fmaf(t0, w, acc);
  }
  c1[j] = acc;
  float s = g1[j] * rsqrtf(v1[j] + EPS);
  s1[j] = s;
  u1[j] = fmaf(b1[j] - m1[j], s, be1[j]);  // h = relu(agg*s1 + u1)
}

__global__ void k_zero4(int4* __restrict__ p, int n4) {
  int i = blockIdx.x * blockDim.x + threadIdx.x;
  if (i < n4) p[i] = make_int4(0, 0, 0, 0);
}

// ---------- bucket edges by dst in ONE pass: slot[d*CAP + cursor++] = src ----------
__global__ __launch_bounds__(256) void k_bucket(const int* __restrict__ esrc,
                                                const int* __restrict__ edst,
                                                int* __restrict__ wcnt,
                                                int* __restrict__ slot, int e) {
  int i = blockIdx.x * blockDim.x + threadIdx.x;
  if (i >= e) return;
  int d = edst[i];
  int p = atomicAdd(&wcnt[d * CSTRIDE], 1);
  if (p < CAP) slot[((size_t)d << 7) + p] = esrc[i];
}

__global__ void k_dinv(const int* __restrict__ wcnt, float* __restrict__ dinv, int n) {
  int i = blockIdx.x * blockDim.x + threadIdx.x;
  if (i < n) dinv[i] = rsqrtf((float)wcnt[i * CSTRIDE] + 1.0f);  // +1 = self-loop
}

// ---------- GEMM1: xs = bf16((x @ W1p + c1) * dinv[row])   (fp32 vector ALU) ----------
__global__ __launch_bounds__(256) void k_gemm1(const float* __restrict__ x,
                                               const float* __restrict__ W1p,
                                               const float* __restrict__ c1,
                                               const float* __restrict__ dinv,
                                               unsigned short* __restrict__ xsb, int n) {
  __shared__ float wlds[64 * 128];   // 32 KB, half of W at a time
  __shared__ float xlds[32 * 132];   // stride 132: 16B-aligned rows + no bank conflict
  const int tid = threadIdx.x;
  const int r0 = blockIdx.x * 32;
  for (int j = 0; j < 4; ++j) {
    int q = tid + 256 * j;
    int row = q >> 5, c4 = q & 31;
    float4 v = make_float4(0.f, 0.f, 0.f, 0.f);
    if (r0 + row < n) v = ((const float4*)x)[(size_t)(r0 + row) * 32 + c4];
    float* p = &xlds[row * 132 + c4 * 4];
    p[0] = v.x; p[1] = v.y; p[2] = v.z; p[3] = v.w;
  }
  const int cg = tid & 31, rg = tid >> 5;
  float4 acc0 = {0,0,0,0}, acc1 = {0,0,0,0}, acc2 = {0,0,0,0}, acc3 = {0,0,0,0};
  for (int kb = 0; kb < 2; ++kb) {
    __syncthreads();
    for (int j = 0; j < 8; ++j) {
      int q = tid + 256 * j;
      ((float4*)wlds)[q] = ((const float4*)W1p)[kb * 2048 + q];
    }
    __syncthreads();
    for (int k = 0; k < 64; k += 4) {
      int kg = kb * 64 + k;
      float4 x0 = *(float4*)&xlds[(rg * 4 + 0) * 132 + kg];
      float4 x1 = *(float4*)&xlds[(rg * 4 + 1) * 132 + kg];
      float4 x2 = *(float4*)&xlds[(rg * 4 + 2) * 132 + kg];
      float4 x3 = *(float4*)&xlds[(rg * 4 + 3) * 132 + kg];
      float4 w0 = *(float4*)&wlds[(k + 0) * 128 + cg * 4];
      float4 w1 = *(float4*)&wlds[(k + 1) * 128 + cg * 4];
      float4 w2 = *(float4*)&wlds[(k + 2) * 128 + cg * 4];
      float4 w3 = *(float4*)&wlds[(k + 3) * 128 + cg * 4];
#define FMA4(A, xsv, W) A.x = fmaf(xsv, W.x, A.x); A.y = fmaf(xsv, W.y, A.y); \
                        A.z = fmaf(xsv, W.z, A.z); A.w = fmaf(xsv, W.w, A.w)
      FMA4(acc0, x0.x, w0); FMA4(acc0, x0.y, w1); FMA4(acc0, x0.z, w2); FMA4(acc0, x0.w, w3);
      FMA4(acc1, x1.x, w0); FMA4(acc1, x1.y, w1); FMA4(acc1, x1.z, w2); FMA4(acc1, x1.w, w3);
      FMA4(acc2, x2.x, w0); FMA4(acc2, x2.y, w1); FMA4(acc2, x2.z, w2); FMA4(acc2, x2.w, w3);
      FMA4(acc3, x3.x, w0); FMA4(acc3, x3.y, w1); FMA4(acc3, x3.z, w2); FMA4(acc3, x3.w, w3);
#undef FMA4
    }
  }
  float4 cv = *(const float4*)&c1[cg * 4];
  int r = r0 + rg * 4;
#define STORE_ROW(A, RR) if (RR < n) { float dd = dinv[RR]; \
    ushort4 us; us.x = f2bf((A.x + cv.x) * dd); us.y = f2bf((A.y + cv.y) * dd); \
    us.z = f2bf((A.z + cv.z) * dd); us.w = f2bf((A.w + cv.w) * dd); \
    ((ushort4*)xsb)[(size_t)(RR) * 32 + cg] = us; }
  STORE_ROW(acc0, r + 0); STORE_ROW(acc1, r + 1); STORE_ROW(acc2, r + 2); STORE_ROW(acc3, r + 3);
#undef STORE_ROW
}

// ---------- gather1 fused BN1+ReLU+GEMM2: one wave per dst node ----------
// agg = dinv[d]*(xs[d] + sum xs[src]); h = relu(agg*s1+u1); xs2[d] = (h @ W2) * dinv[d]
__global__ __launch_bounds__(256) void k_gather1(const int* __restrict__ wcnt,
                                                 const int* __restrict__ slot,
                                                 const unsigned short* __restrict__ xsb,
                                                 const float* __restrict__ dinv,
                                                 const float* __restrict__ s1,
                                                 const float* __restrict__ u1,
                                                 const float* __restrict__ W2,
                                                 float* __restrict__ xs2, int n) {
  int wave = threadIdx.x >> 6, lane = threadIdx.x & 63;
  int d = blockIdx.x * 4 + wave;
  if (d >= n) return;
  const uint* xsv = (const uint*)xsb;  // ushort2 packed as uint; 2 channels/lane
  uint self = xsv[(size_t)d * 64 + lane];
  float ax = bf2f((unsigned short)(self & 0xffff));
  float ay = bf2f((unsigned short)(self >> 16));
  int cnt = wcnt[d * CSTRIDE]; if (cnt > CAP) cnt = CAP;
  const int* slotd = slot + ((size_t)d << 7);
  int k = 0;
  for (; k + 3 < cnt; k += 4) {   // 4 row-loads in flight
    int s0 = slotd[k], s1i = slotd[k + 1], s2 = slotd[k + 2], s3 = slotd[k + 3];
    uint v0 = xsv[(size_t)s0 * 64 + lane];
    uint v1 = xsv[(size_t)s1i * 64 + lane];
    uint v2 = xsv[(size_t)s2 * 64 + lane];
    uint v3 = xsv[(size_t)s3 * 64 + lane];
    ax += bf2f((unsigned short)(v0 & 0xffff)) + bf2f((unsigned short)(v1 & 0xffff))
        + bf2f((unsigned short)(v2 & 0xffff)) + bf2f((unsigned short)(v3 & 0xffff));
    ay += bf2f((unsigned short)(v0 >> 16)) + bf2f((unsigned short)(v1 >> 16))
        + bf2f((unsigned short)(v2 >> 16)) + bf2f((unsigned short)(v3 >> 16));
  }
  for (; k < cnt; ++k) {
    uint v = xsv[(size_t)slotd[k] * 64 + lane];
    ax += bf2f((unsigned short)(v & 0xffff));
    ay += bf2f((unsigned short)(v >> 16));
  }
  float dd = dinv[d];
  float2 sv = ((const float2*)s1)[lane];
  float2 uv = ((const float2*)u1)[lane];
  float h0 = fmaxf(fmaf(ax * dd, sv.x, uv.x), 0.f);
  float h1 = fmaxf(fmaf(ay * dd, sv.y, uv.y), 0.f);
  float4 w = ((const float4*)W2)[lane];  // {W2[2l][0],W2[2l][1],W2[2l+1][0],W2[2l+1][1]}
  float p0 = fmaf(h0, w.x, h1 * w.z);
  float p1 = fmaf(h0, w.y, h1 * w.w);
  for (int off = 32; off > 0; off >>= 1) {
    p0 += __shfl_down(p0, off);
    p1 += __shfl_down(p1, off);
  }
  if (lane == 0) ((float2*)xs2)[d] = make_float2(p0 * dd, p1 * dd);
}

// ---------- gather2: out[d] = b2 + dinv[d]*(xs2[d] + sum xs2[src]) ----------
__global__ __launch_bounds__(256) void k_gather2(const int* __restrict__ wcnt,
                                                 const int* __restrict__ slot,
                                                 const float* __restrict__ xs2,
                                                 const float* __restrict__ dinv,
                                                 const float* __restrict__ b2,
                                                 float* __restrict__ out, int n) {
  int wave = threadIdx.x >> 6, lane = threadIdx.x & 63;
  int d = blockIdx.x * 4 + wave;
  if (d >= n) return;
  int cnt = wcnt[d * CSTRIDE]; if (cnt > CAP) cnt = CAP;
  const int* slotd = slot + ((size_t)d << 7);
  float p0 = 0.f, p1 = 0.f;
  for (int k = lane; k < cnt; k += 64) {
    int s = slotd[k];
    float2 v = ((const float2*)xs2)[s];
    p0 += v.x; p1 += v.y;
  }
  for (int off = 32; off > 0; off >>= 1) {
    p0 += __shfl_down(p0, off);
    p1 += __shfl_down(p1, off);
  }
  if (lane == 0) {
    float dd = dinv[d];
    float2 self = ((const float2*)xs2)[d];
    out[d * 2 + 0] = fmaf(dd, p0 + self.x, b2[0]);
    out[d * 2 + 1] = fmaf(dd, p1 + self.y, b2[1]);
  }
}

extern "C" void kernel_launch(void* const* d_in, const int* in_sizes, int n_in,
                              void* d_out, int out_size, void* d_ws, size_t ws_size,
                              hipStream_t stream) {
  const float* x   = (const float*)d_in[0];
  const int*   ei  = (const int*)d_in[1];
  const float* g0  = (const float*)d_in[2];
  const float* be0 = (const float*)d_in[3];
  const float* m0  = (const float*)d_in[4];
  const float* v0  = (const float*)d_in[5];
  const float* W1  = (const float*)d_in[6];
  const float* b1  = (const float*)d_in[7];
  const float* g1  = (const float*)d_in[8];
  const float* be1 = (const float*)d_in[9];
  const float* m1  = (const float*)d_in[10];
  const float* v1  = (const float*)d_in[11];
  const float* W2  = (const float*)d_in[12];
  const float* b2  = (const float*)d_in[13];
  float* out = (float*)d_out;

  const int n = in_sizes[0] / 128;
  const int e = in_sizes[1] / 2;
  const int* esrc = ei;
  const int* edst = ei + e;

  // workspace layout (all 16B-aligned; n=50000) — total ~45.8 MB
  int*   wcnt = (int*)d_ws;                          // n*CSTRIDE ints (6.4 MB, padded cursors)
  int*   slot = wcnt + (size_t)n * CSTRIDE;          // n*CAP ints (25.6 MB)
  float* dinv = (float*)(slot + (size_t)n * CAP);    // n
  float* W1p  = dinv + n;                            // 128*128
  float* c1   = W1p + 128 * 128;                     // 128
  float* s1   = c1 + 128;                            // 128
  float* u1   = s1 + 128;                            // 128
  unsigned short* xsb = (unsigned short*)(u1 + 128); // n*128 bf16 (12.8 MB)
  float* xs2  = (float*)(xsb + (size_t)n * 128);     // n*2

  const int nc4 = n * CSTRIDE / 4;
  k_zero4<<<(nc4 + 255) / 256, 256, 0, stream>>>((int4*)wcnt, nc4);
  k_prep<<<1, 128, 0, stream>>>(W1, b1, g0, be0, m0, v0, g1, be1, m1, v1, W1p, c1, s1, u1);
  k_bucket<<<(e + 255) / 256, 256, 0, stream>>>(esrc, edst, wcnt, slot, e);
  k_dinv<<<(n + 255) / 256, 256, 0, stream>>>(wcnt, dinv, n);
  k_gemm1<<<(n + 31) / 32, 256, 0, stream>>>(x, W1p, c1, dinv, xsb, n);
  k_gather1<<<(n + 3) / 4, 256, 0, stream>>>(wcnt, slot, xsb, dinv, s1, u1, W2, xs2, n);
  k_gather2<<<(n + 3) / 4, 256, 0, stream>>>(wcnt, slot, xs2, dinv, b2, out, n);
}

// Round 4
// 353.609 us; speedup vs baseline: 2.8708x; 2.8708x over previous
//
#include <hip/hip_runtime.h>

#define EPS 1e-5f
#define CAP 128           // slots per dst bucket (deg ~ Poisson(32); P(>=128) ~ 1e-40)
#define CSTRIDE 32        // cursor padding: 32 ints = 128 B, one cacheline per dst

// branchless RNE fp32->bf16 (identical to __float2bfloat16 for finite inputs)
__device__ __forceinline__ unsigned short f2bf(float f) {
  union { float f; unsigned int u; } v; v.f = f;
  unsigned int r = (v.u + 0x7fffu + ((v.u >> 16) & 1u)) >> 16;
  return (unsigned short)r;
}
__device__ __forceinline__ float bf2f(unsigned short u) {
  union { unsigned int i; float f; } v; v.i = ((unsigned int)u) << 16; return v.f;
}

// ---------- prep: fold BN0 into W1 (W1p = diag(s0)W1, c1 = t0@W1), BN1 affine (s1,u1) ----------
__global__ void k_prep(const float* __restrict__ W1, const float* __restrict__ b1,
                       const float* __restrict__ g0, const float* __restrict__ be0,
                       const float* __restrict__ m0, const float* __restrict__ v0,
                       const float* __restrict__ g1, const float* __restrict__ be1,
                       const float* __restrict__ m1, const float* __restrict__ v1,
                       float* __restrict__ W1p, float* __restrict__ c1,
                       float* __restrict__ s1, float* __restrict__ u1) {
  int j = threadIdx.x;  // 128 threads, one per output column
  float acc = 0.f;
  for (int k = 0; k < 128; ++k) {
    float s0 = g0[k] * rsqrtf(v0[k] + EPS);
    float t0 = be0[k] - m0[k] * s0;
    float w = W1[k * 128 + j];
    W1p[k * 128 + j] = s0 * w;
    acc = fmaf(t0, w, acc);
  }
  c1[j] = acc;
  float s = g1[j] * rsqrtf(v1[j] + EPS);
  s1[j] = s;
  u1[j] = fmaf(b1[j] - m1[j], s, be1[j]);  // h = relu(agg*s1 + u1)
}

__global__ void k_zero4(int4* __restrict__ p, int n4) {
  int i = blockIdx.x * blockDim.x + threadIdx.x;
  if (i < n4) p[i] = make_int4(0, 0, 0, 0);
}

// ---------- bucket edges by dst in ONE pass: slot[d*CAP + cursor++] = src ----------
__global__ __launch_bounds__(256) void k_bucket(const int* __restrict__ esrc,
                                                const int* __restrict__ edst,
                                                int* __restrict__ wcnt,
                                                int* __restrict__ slot, int e) {
  int i = blockIdx.x * blockDim.x + threadIdx.x;
  if (i >= e) return;
  int d = edst[i];
  int p = atomicAdd(&wcnt[d * CSTRIDE], 1);
  if (p < CAP) slot[((size_t)d << 7) + p] = esrc[i];
}

__global__ void k_dinv(const int* __restrict__ wcnt, float* __restrict__ dinv, int n) {
  int i = blockIdx.x * blockDim.x + threadIdx.x;
  if (i < n) dinv[i] = rsqrtf((float)wcnt[i * CSTRIDE] + 1.0f);  // +1 = self-loop
}

// ---------- GEMM1: xsf = (x @ W1p + c1) * dinv[row]   (fp32 vector ALU, R2-proven codegen) ----------
__global__ __launch_bounds__(256) void k_gemm1(const float* __restrict__ x,
                                               const float* __restrict__ W1p,
                                               const float* __restrict__ c1,
                                               const float* __restrict__ dinv,
                                               float* __restrict__ xs, int n) {
  __shared__ float wlds[64 * 128];   // 32 KB, half of W at a time
  __shared__ float xlds[32 * 132];   // stride 132: 16B-aligned rows + no bank conflict
  const int tid = threadIdx.x;
  const int r0 = blockIdx.x * 32;
  for (int j = 0; j < 4; ++j) {
    int q = tid + 256 * j;
    int row = q >> 5, c4 = q & 31;
    float4 v = make_float4(0.f, 0.f, 0.f, 0.f);
    if (r0 + row < n) v = ((const float4*)x)[(size_t)(r0 + row) * 32 + c4];
    float* p = &xlds[row * 132 + c4 * 4];
    p[0] = v.x; p[1] = v.y; p[2] = v.z; p[3] = v.w;
  }
  const int cg = tid & 31, rg = tid >> 5;
  float4 acc0 = {0,0,0,0}, acc1 = {0,0,0,0}, acc2 = {0,0,0,0}, acc3 = {0,0,0,0};
  for (int kb = 0; kb < 2; ++kb) {
    __syncthreads();
    for (int j = 0; j < 8; ++j) {
      int q = tid + 256 * j;
      ((float4*)wlds)[q] = ((const float4*)W1p)[kb * 2048 + q];
    }
    __syncthreads();
    for (int k = 0; k < 64; k += 4) {
      int kg = kb * 64 + k;
      float4 x0 = *(float4*)&xlds[(rg * 4 + 0) * 132 + kg];
      float4 x1 = *(float4*)&xlds[(rg * 4 + 1) * 132 + kg];
      float4 x2 = *(float4*)&xlds[(rg * 4 + 2) * 132 + kg];
      float4 x3 = *(float4*)&xlds[(rg * 4 + 3) * 132 + kg];
      float4 w0 = *(float4*)&wlds[(k + 0) * 128 + cg * 4];
      float4 w1 = *(float4*)&wlds[(k + 1) * 128 + cg * 4];
      float4 w2 = *(float4*)&wlds[(k + 2) * 128 + cg * 4];
      float4 w3 = *(float4*)&wlds[(k + 3) * 128 + cg * 4];
#define FMA4(A, xsv, W) A.x = fmaf(xsv, W.x, A.x); A.y = fmaf(xsv, W.y, A.y); \
                        A.z = fmaf(xsv, W.z, A.z); A.w = fmaf(xsv, W.w, A.w)
      FMA4(acc0, x0.x, w0); FMA4(acc0, x0.y, w1); FMA4(acc0, x0.z, w2); FMA4(acc0, x0.w, w3);
      FMA4(acc1, x1.x, w0); FMA4(acc1, x1.y, w1); FMA4(acc1, x1.z, w2); FMA4(acc1, x1.w, w3);
      FMA4(acc2, x2.x, w0); FMA4(acc2, x2.y, w1); FMA4(acc2, x2.z, w2); FMA4(acc2, x2.w, w3);
      FMA4(acc3, x3.x, w0); FMA4(acc3, x3.y, w1); FMA4(acc3, x3.z, w2); FMA4(acc3, x3.w, w3);
#undef FMA4
    }
  }
  float4 cv = *(const float4*)&c1[cg * 4];
  int r = r0 + rg * 4;
#define STORE_ROW(A, RR) if (RR < n) { float dd = dinv[RR]; \
    ((float4*)xs)[(size_t)(RR) * 32 + cg] = make_float4((A.x + cv.x) * dd, (A.y + cv.y) * dd, \
                                                        (A.z + cv.z) * dd, (A.w + cv.w) * dd); }
  STORE_ROW(acc0, r + 0); STORE_ROW(acc1, r + 1); STORE_ROW(acc2, r + 2); STORE_ROW(acc3, r + 3);
#undef STORE_ROW
}

// ---------- cvt: xsb = bf16(xsf), streaming, float4 -> ushort4 ----------
__global__ __launch_bounds__(256) void k_cvt(const float4* __restrict__ xsf,
                                             ushort4* __restrict__ xsb, int n4) {
  int i = blockIdx.x * blockDim.x + threadIdx.x;
  if (i >= n4) return;
  float4 v = xsf[i];
  ushort4 o;
  o.x = f2bf(v.x); o.y = f2bf(v.y); o.z = f2bf(v.z); o.w = f2bf(v.w);
  xsb[i] = o;
}

// ---------- gather1 fused BN1+ReLU+GEMM2: one wave per dst node ----------
// agg = dinv[d]*(xs[d] + sum xs[src]); h = relu(agg*s1+u1); xs2[d] = (h @ W2) * dinv[d]
__global__ __launch_bounds__(256) void k_gather1(const int* __restrict__ wcnt,
                                                 const int* __restrict__ slot,
                                                 const unsigned short* __restrict__ xsb,
                                                 const float* __restrict__ dinv,
                                                 const float* __restrict__ s1,
                                                 const float* __restrict__ u1,
                                                 const float* __restrict__ W2,
                                                 float* __restrict__ xs2, int n) {
  int wave = threadIdx.x >> 6, lane = threadIdx.x & 63;
  int d = blockIdx.x * 4 + wave;
  if (d >= n) return;
  const uint* xsv = (const uint*)xsb;  // ushort2 packed as uint; 2 channels/lane
  uint self = xsv[(size_t)d * 64 + lane];
  float ax = bf2f((unsigned short)(self & 0xffff));
  float ay = bf2f((unsigned short)(self >> 16));
  int cnt = wcnt[d * CSTRIDE]; if (cnt > CAP) cnt = CAP;
  const int* slotd = slot + ((size_t)d << 7);
  int k = 0;
  for (; k + 3 < cnt; k += 4) {   // 4 row-loads in flight
    int s0 = slotd[k], s1i = slotd[k + 1], s2 = slotd[k + 2], s3 = slotd[k + 3];
    uint v0 = xsv[(size_t)s0 * 64 + lane];
    uint v1 = xsv[(size_t)s1i * 64 + lane];
    uint v2 = xsv[(size_t)s2 * 64 + lane];
    uint v3 = xsv[(size_t)s3 * 64 + lane];
    ax += bf2f((unsigned short)(v0 & 0xffff)) + bf2f((unsigned short)(v1 & 0xffff))
        + bf2f((unsigned short)(v2 & 0xffff)) + bf2f((unsigned short)(v3 & 0xffff));
    ay += bf2f((unsigned short)(v0 >> 16)) + bf2f((unsigned short)(v1 >> 16))
        + bf2f((unsigned short)(v2 >> 16)) + bf2f((unsigned short)(v3 >> 16));
  }
  for (; k < cnt; ++k) {
    uint v = xsv[(size_t)slotd[k] * 64 + lane];
    ax += bf2f((unsigned short)(v & 0xffff));
    ay += bf2f((unsigned short)(v >> 16));
  }
  float dd = dinv[d];
  float2 sv = ((const float2*)s1)[lane];
  float2 uv = ((const float2*)u1)[lane];
  float h0 = fmaxf(fmaf(ax * dd, sv.x, uv.x), 0.f);
  float h1 = fmaxf(fmaf(ay * dd, sv.y, uv.y), 0.f);
  float4 w = ((const float4*)W2)[lane];  // {W2[2l][0],W2[2l][1],W2[2l+1][0],W2[2l+1][1]}
  float p0 = fmaf(h0, w.x, h1 * w.z);
  float p1 = fmaf(h0, w.y, h1 * w.w);
  for (int off = 32; off > 0; off >>= 1) {
    p0 += __shfl_down(p0, off);
    p1 += __shfl_down(p1, off);
  }
  if (lane == 0) ((float2*)xs2)[d] = make_float2(p0 * dd, p1 * dd);
}

// ---------- gather2: out[d] = b2 + dinv[d]*(xs2[d] + sum xs2[src]) ----------
__global__ __launch_bounds__(256) void k_gather2(const int* __restrict__ wcnt,
                                                 const int* __restrict__ slot,
                                                 const float* __restrict__ xs2,
                                                 const float* __restrict__ dinv,
                                                 const float* __restrict__ b2,
                                                 float* __restrict__ out, int n) {
  int wave = threadIdx.x >> 6, lane = threadIdx.x & 63;
  int d = blockIdx.x * 4 + wave;
  if (d >= n) return;
  int cnt = wcnt[d * CSTRIDE]; if (cnt > CAP) cnt = CAP;
  const int* slotd = slot + ((size_t)d << 7);
  float p0 = 0.f, p1 = 0.f;
  for (int k = lane; k < cnt; k += 64) {
    int s = slotd[k];
    float2 v = ((const float2*)xs2)[s];
    p0 += v.x; p1 += v.y;
  }
  for (int off = 32; off > 0; off >>= 1) {
    p0 += __shfl_down(p0, off);
    p1 += __shfl_down(p1, off);
  }
  if (lane == 0) {
    float dd = dinv[d];
    float2 self = ((const float2*)xs2)[d];
    out[d * 2 + 0] = fmaf(dd, p0 + self.x, b2[0]);
    out[d * 2 + 1] = fmaf(dd, p1 + self.y, b2[1]);
  }
}

extern "C" void kernel_launch(void* const* d_in, const int* in_sizes, int n_in,
                              void* d_out, int out_size, void* d_ws, size_t ws_size,
                              hipStream_t stream) {
  const float* x   = (const float*)d_in[0];
  const int*   ei  = (const int*)d_in[1];
  const float* g0  = (const float*)d_in[2];
  const float* be0 = (const float*)d_in[3];
  const float* m0  = (const float*)d_in[4];
  const float* v0  = (const float*)d_in[5];
  const float* W1  = (const float*)d_in[6];
  const float* b1  = (const float*)d_in[7];
  const float* g1  = (const float*)d_in[8];
  const float* be1 = (const float*)d_in[9];
  const float* m1  = (const float*)d_in[10];
  const float* v1  = (const float*)d_in[11];
  const float* W2  = (const float*)d_in[12];
  const float* b2  = (const float*)d_in[13];
  float* out = (float*)d_out;

  const int n = in_sizes[0] / 128;
  const int e = in_sizes[1] / 2;
  const int* esrc = ei;
  const int* edst = ei + e;

  // workspace layout (all 16B-aligned; n=50000) — total ~71 MB
  int*   wcnt = (int*)d_ws;                          // n*CSTRIDE ints (6.4 MB, padded cursors)
  int*   slot = wcnt + (size_t)n * CSTRIDE;          // n*CAP ints (25.6 MB)
  float* dinv = (float*)(slot + (size_t)n * CAP);    // n
  float* W1p  = dinv + n;                            // 128*128
  float* c1   = W1p + 128 * 128;                     // 128
  float* s1   = c1 + 128;                            // 128
  float* u1   = s1 + 128;                            // 128
  float* xsf  = u1 + 128;                            // n*128 fp32 (25.6 MB)
  unsigned short* xsb = (unsigned short*)(xsf + (size_t)n * 128); // n*128 bf16 (12.8 MB)
  float* xs2  = (float*)(xsb + (size_t)n * 128);     // n*2

  const int nc4 = n * CSTRIDE / 4;
  k_zero4<<<(nc4 + 255) / 256, 256, 0, stream>>>((int4*)wcnt, nc4);
  k_prep<<<1, 128, 0, stream>>>(W1, b1, g0, be0, m0, v0, g1, be1, m1, v1, W1p, c1, s1, u1);
  k_bucket<<<(e + 255) / 256, 256, 0, stream>>>(esrc, edst, wcnt, slot, e);
  k_dinv<<<(n + 255) / 256, 256, 0, stream>>>(wcnt, dinv, n);
  k_gemm1<<<(n + 31) / 32, 256, 0, stream>>>(x, W1p, c1, dinv, xsf, n);
  k_cvt<<<(n * 32 + 255) / 256, 256, 0, stream>>>((const float4*)xsf, (ushort4*)xsb, n * 32);
  k_gather1<<<(n + 3) / 4, 256, 0, stream>>>(wcnt, slot, xsb, dinv, s1, u1, W2, xs2, n);
  k_gather2<<<(n + 3) / 4, 256, 0, stream>>>(wcnt, slot, xs2, dinv, b2, out, n);
}

// Round 5
// 262.900 us; speedup vs baseline: 3.8613x; 1.3450x over previous
//
#include <hip/hip_runtime.h>

#define EPS 1e-5f
#define CAP 128           // slots per dst (deg ~ Poisson(32); P(>=128) ~ 1e-40)
#define DR  128           // dsts per coarse bucket
#define NB  391           // ceil(50000/128) coarse buckets
#define CB  4608          // pairs per coarse bucket (mean 4096, +8 sigma)
#define GS  16            // gcur padding: 16 ints = 64B line per bucket
#define CHUNK 4096        // edges per phase-1 workgroup

// branchless RNE fp32->bf16 (identical to __float2bfloat16 for finite inputs)
__device__ __forceinline__ unsigned short f2bf(float f) {
  union { float f; unsigned int u; } v; v.f = f;
  unsigned int r = (v.u + 0x7fffu + ((v.u >> 16) & 1u)) >> 16;
  return (unsigned short)r;
}
__device__ __forceinline__ float bf2f(unsigned short u) {
  union { unsigned int i; float f; } v; v.i = ((unsigned int)u) << 16; return v.f;
}

// ---------- prep: fold BN0 into W1 (W1p = diag(s0)W1, c1 = t0@W1), BN1 affine (s1,u1) ----------
__global__ void k_prep(const float* __restrict__ W1, const float* __restrict__ b1,
                       const float* __restrict__ g0, const float* __restrict__ be0,
                       const float* __restrict__ m0, const float* __restrict__ v0,
                       const float* __restrict__ g1, const float* __restrict__ be1,
                       const float* __restrict__ m1, const float* __restrict__ v1,
                       float* __restrict__ W1p, float* __restrict__ c1,
                       float* __restrict__ s1, float* __restrict__ u1) {
  int j = threadIdx.x;  // 128 threads, one per output column
  float acc = 0.f;
  for (int k = 0; k < 128; ++k) {
    float s0 = g0[k] * rsqrtf(v0[k] + EPS);
    float t0 = be0[k] - m0[k] * s0;
    float w = W1[k * 128 + j];
    W1p[k * 128 + j] = s0 * w;
    acc = fmaf(t0, w, acc);
  }
  c1[j] = acc;
  float s = g1[j] * rsqrtf(v1[j] + EPS);
  s1[j] = s;
  u1[j] = fmaf(b1[j] - m1[j], s, be1[j]);  // h = relu(agg*s1 + u1)
}

__global__ void k_zero4(int4* __restrict__ p, int n4) {
  int i = blockIdx.x * blockDim.x + threadIdx.x;
  if (i < n4) p[i] = make_int4(0, 0, 0, 0);
}

// ---------- phase 1: coarse-bin edges (128 dsts/bucket) with dense appends ----------
__global__ __launch_bounds__(256) void k_p1(const int* __restrict__ esrc,
                                            const int* __restrict__ edst,
                                            int* __restrict__ gcur,
                                            uint2* __restrict__ coarse, int e) {
  __shared__ int hist[NB];
  __shared__ int base[NB];
  __shared__ int loff[NB];
  for (int i = threadIdx.x; i < NB; i += 256) { hist[i] = 0; loff[i] = 0; }
  __syncthreads();
  int e0 = blockIdx.x * CHUNK;
  int e1 = min(e0 + CHUNK, e);
  for (int i = e0 + threadIdx.x; i < e1; i += 256)
    atomicAdd(&hist[edst[i] >> 7], 1);
  __syncthreads();
  for (int b = threadIdx.x; b < NB; b += 256) {
    int h = hist[b];
    if (h > 0) base[b] = atomicAdd(&gcur[b * GS], h);
  }
  __syncthreads();
  for (int i = e0 + threadIdx.x; i < e1; i += 256) {
    int d = edst[i], s = esrc[i];
    int b = d >> 7;
    int p = base[b] + atomicAdd(&loff[b], 1);
    if (p < CB) coarse[(size_t)b * CB + p] = make_uint2((uint)s, (uint)d);
  }
}

// ---------- phase 2: LDS fine-bin one coarse bucket -> dense slot tile + wcnt + dinv ----------
__global__ __launch_bounds__(256) void k_p2(const int* __restrict__ gcur,
                                            const uint2* __restrict__ coarse,
                                            int* __restrict__ slot,
                                            int* __restrict__ wcnt,
                                            float* __restrict__ dinv, int n) {
  __shared__ int lcnt[DR];
  __shared__ int lslot[DR * CAP];   // 64 KB
  for (int i = threadIdx.x; i < DR; i += 256) lcnt[i] = 0;
  __syncthreads();
  int cb = blockIdx.x;
  int cnt = gcur[cb * GS]; if (cnt > CB) cnt = CB;
  const uint2* src = coarse + (size_t)cb * CB;
  for (int i = threadIdx.x; i < cnt; i += 256) {
    uint2 pr = src[i];
    int ld = (int)(pr.y & 127u);
    int pos = atomicAdd(&lcnt[ld], 1);
    if (pos < CAP) lslot[ld * CAP + pos] = (int)pr.x;
  }
  __syncthreads();
  int dbase = cb * DR;
  for (int ld = threadIdx.x; ld < DR; ld += 256) {
    int d = dbase + ld;
    if (d < n) {
      int c = min(lcnt[ld], CAP);
      wcnt[d] = c;
      dinv[d] = rsqrtf((float)c + 1.0f);
    }
  }
  // dense streaming store of the whole tile (unused tail slots are never read)
  for (int q = threadIdx.x; q < DR * CAP; q += 256) {
    if (dbase + (q >> 7) < n) slot[(size_t)cb * (DR * CAP) + q] = lslot[q];
  }
}

// ---------- GEMM1: xsf = (x @ W1p + c1) * dinv[row]   (fp32 vector ALU, proven codegen) ----------
__global__ __launch_bounds__(256) void k_gemm1(const float* __restrict__ x,
                                               const float* __restrict__ W1p,
                                               const float* __restrict__ c1,
                                               const float* __restrict__ dinv,
                                               float* __restrict__ xs, int n) {
  __shared__ float wlds[64 * 128];   // 32 KB, half of W at a time
  __shared__ float xlds[32 * 132];   // stride 132: 16B-aligned rows + no bank conflict
  const int tid = threadIdx.x;
  const int r0 = blockIdx.x * 32;
  for (int j = 0; j < 4; ++j) {
    int q = tid + 256 * j;
    int row = q >> 5, c4 = q & 31;
    float4 v = make_float4(0.f, 0.f, 0.f, 0.f);
    if (r0 + row < n) v = ((const float4*)x)[(size_t)(r0 + row) * 32 + c4];
    float* p = &xlds[row * 132 + c4 * 4];
    p[0] = v.x; p[1] = v.y; p[2] = v.z; p[3] = v.w;
  }
  const int cg = tid & 31, rg = tid >> 5;
  float4 acc0 = {0,0,0,0}, acc1 = {0,0,0,0}, acc2 = {0,0,0,0}, acc3 = {0,0,0,0};
  for (int kb = 0; kb < 2; ++kb) {
    __syncthreads();
    for (int j = 0; j < 8; ++j) {
      int q = tid + 256 * j;
      ((float4*)wlds)[q] = ((const float4*)W1p)[kb * 2048 + q];
    }
    __syncthreads();
    for (int k = 0; k < 64; k += 4) {
      int kg = kb * 64 + k;
      float4 x0 = *(float4*)&xlds[(rg * 4 + 0) * 132 + kg];
      float4 x1 = *(float4*)&xlds[(rg * 4 + 1) * 132 + kg];
      float4 x2 = *(float4*)&xlds[(rg * 4 + 2) * 132 + kg];
      float4 x3 = *(float4*)&xlds[(rg * 4 + 3) * 132 + kg];
      float4 w0 = *(float4*)&wlds[(k + 0) * 128 + cg * 4];
      float4 w1 = *(float4*)&wlds[(k + 1) * 128 + cg * 4];
      float4 w2 = *(float4*)&wlds[(k + 2) * 128 + cg * 4];
      float4 w3 = *(float4*)&wlds[(k + 3) * 128 + cg * 4];
#define FMA4(A, xsv, W) A.x = fmaf(xsv, W.x, A.x); A.y = fmaf(xsv, W.y, A.y); \
                        A.z = fmaf(xsv, W.z, A.z); A.w = fmaf(xsv, W.w, A.w)
      FMA4(acc0, x0.x, w0); FMA4(acc0, x0.y, w1); FMA4(acc0, x0.z, w2); FMA4(acc0, x0.w, w3);
      FMA4(acc1, x1.x, w0); FMA4(acc1, x1.y, w1); FMA4(acc1, x1.z, w2); FMA4(acc1, x1.w, w3);
      FMA4(acc2, x2.x, w0); FMA4(acc2, x2.y, w1); FMA4(acc2, x2.z, w2); FMA4(acc2, x2.w, w3);
      FMA4(acc3, x3.x, w0); FMA4(acc3, x3.y, w1); FMA4(acc3, x3.z, w2); FMA4(acc3, x3.w, w3);
#undef FMA4
    }
  }
  float4 cv = *(const float4*)&c1[cg * 4];
  int r = r0 + rg * 4;
#define STORE_ROW(A, RR) if (RR < n) { float dd = dinv[RR]; \
    ((float4*)xs)[(size_t)(RR) * 32 + cg] = make_float4((A.x + cv.x) * dd, (A.y + cv.y) * dd, \
                                                        (A.z + cv.z) * dd, (A.w + cv.w) * dd); }
  STORE_ROW(acc0, r + 0); STORE_ROW(acc1, r + 1); STORE_ROW(acc2, r + 2); STORE_ROW(acc3, r + 3);
#undef STORE_ROW
}

// ---------- cvt: xsb = bf16(xsf), streaming, float4 -> ushort4 ----------
__global__ __launch_bounds__(256) void k_cvt(const float4* __restrict__ xsf,
                                             ushort4* __restrict__ xsb, int n4) {
  int i = blockIdx.x * blockDim.x + threadIdx.x;
  if (i >= n4) return;
  float4 v = xsf[i];
  ushort4 o;
  o.x = f2bf(v.x); o.y = f2bf(v.y); o.z = f2bf(v.z); o.w = f2bf(v.w);
  xsb[i] = o;
}

// ---------- gather1 fused BN1+ReLU+GEMM2: one wave per dst node ----------
__global__ __launch_bounds__(256) void k_gather1(const int* __restrict__ wcnt,
                                                 const int* __restrict__ slot,
                                                 const unsigned short* __restrict__ xsb,
                                                 const float* __restrict__ dinv,
                                                 const float* __restrict__ s1,
                                                 const float* __restrict__ u1,
                                                 const float* __restrict__ W2,
                                                 float* __restrict__ xs2, int n) {
  int wave = threadIdx.x >> 6, lane = threadIdx.x & 63;
  int d = blockIdx.x * 4 + wave;
  if (d >= n) return;
  const uint* xsv = (const uint*)xsb;  // ushort2 packed as uint; 2 channels/lane
  uint self = xsv[(size_t)d * 64 + lane];
  float ax = bf2f((unsigned short)(self & 0xffff));
  float ay = bf2f((unsigned short)(self >> 16));
  int cnt = wcnt[d]; if (cnt > CAP) cnt = CAP;
  const int* slotd = slot + ((size_t)d << 7);
  int k = 0;
  for (; k + 3 < cnt; k += 4) {   // 4 row-loads in flight
    int s0 = slotd[k], s1i = slotd[k + 1], s2 = slotd[k + 2], s3 = slotd[k + 3];
    uint v0 = xsv[(size_t)s0 * 64 + lane];
    uint v1 = xsv[(size_t)s1i * 64 + lane];
    uint v2 = xsv[(size_t)s2 * 64 + lane];
    uint v3 = xsv[(size_t)s3 * 64 + lane];
    ax += bf2f((unsigned short)(v0 & 0xffff)) + bf2f((unsigned short)(v1 & 0xffff))
        + bf2f((unsigned short)(v2 & 0xffff)) + bf2f((unsigned short)(v3 & 0xffff));
    ay += bf2f((unsigned short)(v0 >> 16)) + bf2f((unsigned short)(v1 >> 16))
        + bf2f((unsigned short)(v2 >> 16)) + bf2f((unsigned short)(v3 >> 16));
  }
  for (; k < cnt; ++k) {
    uint v = xsv[(size_t)slotd[k] * 64 + lane];
    ax += bf2f((unsigned short)(v & 0xffff));
    ay += bf2f((unsigned short)(v >> 16));
  }
  float dd = dinv[d];
  float2 sv = ((const float2*)s1)[lane];
  float2 uv = ((const float2*)u1)[lane];
  float h0 = fmaxf(fmaf(ax * dd, sv.x, uv.x), 0.f);
  float h1 = fmaxf(fmaf(ay * dd, sv.y, uv.y), 0.f);
  float4 w = ((const float4*)W2)[lane];  // {W2[2l][0],W2[2l][1],W2[2l+1][0],W2[2l+1][1]}
  float p0 = fmaf(h0, w.x, h1 * w.z);
  float p1 = fmaf(h0, w.y, h1 * w.w);
  for (int off = 32; off > 0; off >>= 1) {
    p0 += __shfl_down(p0, off);
    p1 += __shfl_down(p1, off);
  }
  if (lane == 0) ((float2*)xs2)[d] = make_float2(p0 * dd, p1 * dd);
}

// ---------- gather2: out[d] = b2 + dinv[d]*(xs2[d] + sum xs2[src]) ----------
__global__ __launch_bounds__(256) void k_gather2(const int* __restrict__ wcnt,
                                                 const int* __restrict__ slot,
                                                 const float* __restrict__ xs2,
                                                 const float* __restrict__ dinv,
                                                 const float* __restrict__ b2,
                                                 float* __restrict__ out, int n) {
  int wave = threadIdx.x >> 6, lane = threadIdx.x & 63;
  int d = blockIdx.x * 4 + wave;
  if (d >= n) return;
  int cnt = wcnt[d]; if (cnt > CAP) cnt = CAP;
  const int* slotd = slot + ((size_t)d << 7);
  float p0 = 0.f, p1 = 0.f;
  for (int k = lane; k < cnt; k += 64) {
    int s = slotd[k];
    float2 v = ((const float2*)xs2)[s];
    p0 += v.x; p1 += v.y;
  }
  for (int off = 32; off > 0; off >>= 1) {
    p0 += __shfl_down(p0, off);
    p1 += __shfl_down(p1, off);
  }
  if (lane == 0) {
    float dd = dinv[d];
    float2 self = ((const float2*)xs2)[d];
    out[d * 2 + 0] = fmaf(dd, p0 + self.x, b2[0]);
    out[d * 2 + 1] = fmaf(dd, p1 + self.y, b2[1]);
  }
}

extern "C" void kernel_launch(void* const* d_in, const int* in_sizes, int n_in,
                              void* d_out, int out_size, void* d_ws, size_t ws_size,
                              hipStream_t stream) {
  const float* x   = (const float*)d_in[0];
  const int*   ei  = (const int*)d_in[1];
  const float* g0  = (const float*)d_in[2];
  const float* be0 = (const float*)d_in[3];
  const float* m0  = (const float*)d_in[4];
  const float* v0  = (const float*)d_in[5];
  const float* W1  = (const float*)d_in[6];
  const float* b1  = (const float*)d_in[7];
  const float* g1  = (const float*)d_in[8];
  const float* be1 = (const float*)d_in[9];
  const float* m1  = (const float*)d_in[10];
  const float* v1  = (const float*)d_in[11];
  const float* W2  = (const float*)d_in[12];
  const float* b2  = (const float*)d_in[13];
  float* out = (float*)d_out;

  const int n = in_sizes[0] / 128;
  const int e = in_sizes[1] / 2;
  const int* esrc = ei;
  const int* edst = ei + e;

  // workspace layout (16B-aligned; n=50000) — ~66 MB
  int*   gcur   = (int*)d_ws;                            // NB*GS ints, padded to 6272
  uint2* coarse = (uint2*)(gcur + 6272);                 // NB*CB pairs (14.4 MB)
  int*   slot   = (int*)(coarse + (size_t)NB * CB);      // n*CAP ints (25.6 MB)
  int*   wcnt   = slot + (size_t)n * CAP;                // n
  float* dinv   = (float*)(wcnt + n);                    // n
  float* W1p    = dinv + n;                              // 128*128
  float* c1     = W1p + 128 * 128;                       // 128
  float* s1     = c1 + 128;                              // 128
  float* u1     = s1 + 128;                              // 128
  float* xsf    = u1 + 128;                              // n*128 fp32 (25.6 MB)
  float* xs2    = xsf + (size_t)n * 128;                 // n*2
  unsigned short* xsb = (unsigned short*)coarse;         // n*128 bf16 — aliases coarse (dead after p2)

  k_zero4<<<(6272 / 4 + 255) / 256, 256, 0, stream>>>((int4*)gcur, 6272 / 4);
  k_prep<<<1, 128, 0, stream>>>(W1, b1, g0, be0, m0, v0, g1, be1, m1, v1, W1p, c1, s1, u1);
  k_p1<<<(e + CHUNK - 1) / CHUNK, 256, 0, stream>>>(esrc, edst, gcur, coarse, e);
  k_p2<<<NB, 256, 0, stream>>>(gcur, coarse, slot, wcnt, dinv, n);
  k_gemm1<<<(n + 31) / 32, 256, 0, stream>>>(x, W1p, c1, dinv, xsf, n);
  k_cvt<<<(n * 32 + 255) / 256, 256, 0, stream>>>((const float4*)xsf, (ushort4*)xsb, n * 32);
  k_gather1<<<(n + 3) / 4, 256, 0, stream>>>(wcnt, slot, xsb, dinv, s1, u1, W2, xs2, n);
  k_gather2<<<(n + 3) / 4, 256, 0, stream>>>(wcnt, slot, xs2, dinv, b2, out, n);
}